// Round 5
// baseline (260.863 us; speedup 1.0000x reference)
//
#include <hip/hip_runtime.h>
#include <math.h>

#define HH 1024
#define WW 1024
#define NPLANES 12              // B*C = 4*3
#define PLANE (HH * WW)

// Tile: 64 wide x 32 tall outputs per 256-thread block.
#define TW 64
#define TH 32
#define RAWR 60                 // TH + 28 rows of chained input
#define RAWC 24                 // 96 cols = 24 float4 chunks (need 92, 16B-aligned)
#define RAWP 100                // pitch; 100 % 32 == 4 (bank-rotates rows)
#define HB1R 60                 // rows of h-blur1
#define HB1P 80                 // 80 cols used/pitch; phases split rows at 16-bank offset
#define X2R  46                 // TH + 14 rows of x2
#define X2P  80
#define HB2R 46
#define HB2P 68                 // overlaid on raw (21.2 KB <= 24 KB)

struct W15 { float w[15]; };

// zero-padded, 16B-aligned-fast-path row load (x multiple of 4)
__device__ inline float4 ld4z(const float* __restrict__ row, int x) {
    if (x >= 0 && x + 3 < WW) return *(const float4*)(row + x);
    float4 r; float* p = (float*)&r;
#pragma unroll
    for (int j = 0; j < 4; ++j) { int xx = x + j; p[j] = (xx >= 0 && xx < WW) ? row[xx] : 0.0f; }
    return r;
}

__device__ inline float chain1(float t, float gain, float gamma, float sb,
                               float hr, float br, float ct) {
    t = t * gain;
    t = __builtin_amdgcn_exp2f(gamma * __log2f(t));          // pow(t,gamma), t>=0
    float hi = __fdividef(1.0f, 1.0f + __expf((0.5f - t) * 10.0f));
    t = t + sb * (1.0f - hi) - hr * hi;
    t = fminf(fmaxf(t, 0.0f), 1.0f);
    t = ct * (t - 0.5f) + 0.5f + br;
    return fminf(fmaxf(t, 0.0f), 1.0f);
}

// ================= Mega-kernel: whole pipeline per 64x32 tile =================
__global__ __launch_bounds__(256, 2) void k_mega(
    const float* __restrict__ x, float* __restrict__ out,
    const float* __restrict__ gains,
    const float* __restrict__ pg, const float* __restrict__ psb,
    const float* __restrict__ phr, const float* __restrict__ pbr,
    const float* __restrict__ pct, const float* __restrict__ penh,
    const float* __restrict__ psoft, const float* __restrict__ pint,
    const float* __restrict__ prot, const float* __restrict__ phard, W15 wk)
{
    __shared__ float raw[RAWR * RAWP];   // 24.0 KB  t0 on [x0-16,x0+80) x [y0-14,y0+46)
    __shared__ float hb1[HB1R * HB1P];   // 19.2 KB  hblur1 on [x0-8,x0+72) x same rows
    __shared__ float x2 [X2R  * X2P ];   // 14.7 KB  x2 on [x0-8,x0+72) x [y0-7,y0+39)
    float* hb2 = raw;                    // reuse: hblur2 on [x0,x0+64) x [y0-7,y0+39)

    const int p   = blockIdx.z;
    const int x0  = blockIdx.x * TW;
    const int y0  = blockIdx.y * TH;
    const int tid = threadIdx.x;
    const float* plane = x + (size_t)p * PLANE;

    const float gain  = gains[p % 3];
    const float gamma = *pg, sb = *psb, hr = *phr, br = *pbr, ct = *pct;
    const float e     = *penh;

    // ---- P0: chain(x) -> raw (24 chunks/row => 8-lane phases never cross rows)
    for (int i = tid; i < RAWR * RAWC; i += 256) {
        int r  = i / RAWC;
        int cc = i - r * RAWC;           // chunk 0..23
        int gy = y0 - 14 + r;
        int xb = x0 - 16 + cc * 4;
        float4 v;
        if (gy >= 0 && gy < HH) {
            float4 f = ld4z(plane + (size_t)gy * WW, xb);
            float* pf = (float*)&f; float* pv = (float*)&v;
#pragma unroll
            for (int j = 0; j < 4; ++j) {
                float cv = chain1(pf[j], gain, gamma, sb, hr, br, ct);
                int xx = xb + j;
                pv[j] = (xx >= 0 && xx < WW) ? cv : 0.0f;   // conv zero-padding
            }
        } else {
            v = make_float4(0.0f, 0.0f, 0.0f, 0.0f);
        }
        *(float4*)&raw[r * RAWP + cc * 4] = v;
    }
    __syncthreads();

    // ---- P1: hblur1 raw -> hb1 (cols 0..79; out col c reads raw c+1..c+15) --
    {
        const int c4 = (tid & 15) * 4;   // 0..60
        const int r0 = tid >> 4;         // 0..15
#pragma unroll
        for (int it = 0; it < 4; ++it) {
            int r = r0 + 16 * it;
            if (r < HB1R) {
                float f[20];
#pragma unroll
                for (int m = 0; m < 5; ++m)
                    *(float4*)&f[4 * m] = *(const float4*)&raw[r * RAWP + c4 + 4 * m];
                float4 o; float* po = (float*)&o;
#pragma unroll
                for (int j = 0; j < 4; ++j) {
                    float acc = 0.0f;
#pragma unroll
                    for (int k = 0; k < 15; ++k) acc += wk.w[k] * f[j + 1 + k];
                    po[j] = acc;
                }
                *(float4*)&hb1[r * HB1P + c4] = o;
            }
        }
        // cols 64..79 (4 chunks x 60 rows; pitch-80 => adjacent rows hit
        // disjoint bank halves within an 8-lane phase)
        const int cB = 64 + (tid & 3) * 4;
        const int rB = tid >> 2;         // 0..63
        if (rB < HB1R) {
            float f[20];
#pragma unroll
            for (int m = 0; m < 5; ++m)
                *(float4*)&f[4 * m] = *(const float4*)&raw[rB * RAWP + cB + 4 * m];
            float4 o; float* po = (float*)&o;
#pragma unroll
            for (int j = 0; j < 4; ++j) {
                float acc = 0.0f;
#pragma unroll
                for (int k = 0; k < 15; ++k) acc += wk.w[k] * f[j + 1 + k];
                po[j] = acc;
            }
            *(float4*)&hb1[rB * HB1P + cB] = o;
        }
    }
    __syncthreads();

    // ---- P2: vblur1 + LCE -> x2 LDS (force 0 outside image for blur2 pad) ---
    if (tid < 240) {
        const int band = tid / 80;       // 0..2
        const int c    = tid - band * 80;
        const int r0b  = band * 16;      // rows r0b .. min(r0b+15, 45)
        const int gx   = x0 - 8 + c;
        const bool colok = (gx >= 0) && (gx < WW);

        float win[15];
#pragma unroll
        for (int k = 0; k < 14; ++k) win[k] = hb1[(r0b + k) * HB1P + c];

#pragma unroll
        for (int j = 0; j < 16; ++j) {
            int rr = r0b + j;
            if (rr < X2R) {
                win[14] = hb1[(rr + 14) * HB1P + c];
                float lm = 0.0f;
#pragma unroll
                for (int k = 0; k < 15; ++k) lm += wk.w[k] * win[k];
                float t0c = raw[(rr + 7) * RAWP + c + 8];
                float v = (1.0f + e) * t0c - e * lm;
                int gy = y0 - 7 + rr;
                x2[rr * X2P + c] = (colok && gy >= 0 && gy < HH) ? v : 0.0f;
#pragma unroll
                for (int k = 0; k < 14; ++k) win[k] = win[k + 1];
            }
        }
    }
    __syncthreads();   // also protects raw before hb2 overlay

    // ---- P3: hblur2 x2 -> hb2 (raw space); out col c reads x2 c+1..c+15 -----
    {
        const int c4 = (tid & 15) * 4;   // 0..60
        const int r0 = tid >> 4;
#pragma unroll
        for (int it = 0; it < 3; ++it) {
            int r = r0 + 16 * it;
            if (r < HB2R) {
                float f[20];
#pragma unroll
                for (int m = 0; m < 5; ++m)
                    *(float4*)&f[4 * m] = *(const float4*)&x2[r * X2P + c4 + 4 * m];
                float4 o; float* po = (float*)&o;
#pragma unroll
                for (int j = 0; j < 4; ++j) {
                    float acc = 0.0f;
#pragma unroll
                    for (int k = 0; k < 15; ++k) acc += wk.w[k] * f[j + 1 + k];
                    po[j] = acc;
                }
                *(float4*)&hb2[r * HB2P + c4] = o;
            }
        }
    }
    __syncthreads();

    // ---- P4: vblur2 + softness + rotated gradient + clip -> global ----------
    {
        const int tx  = tid & 63;
        const int ty  = tid >> 6;        // 4 bands x 8 rows
        const int ly0 = ty * 8;
        const int gx  = x0 + tx;

        const float s     = *psoft;
        const float inten = *pint;
        const float hard  = *phard;
        const float theta = (*prot) * 0.017453292519943295f;
        const float cth = __cosf(theta), sth = __sinf(theta);
        const float base = (-1.0f + 2.0f * (float)gx * (1.0f / (float)(WW - 1))) * cth;

        float win[15];
#pragma unroll
        for (int k = 0; k < 14; ++k) win[k] = hb2[(ly0 + k) * HB2P + tx];

        float* dstP = out + (size_t)p * PLANE;
#pragma unroll
        for (int j = 0; j < 8; ++j) {
            win[14] = hb2[(ly0 + j + 14) * HB2P + tx];
            float bl = 0.0f;
#pragma unroll
            for (int k = 0; k < 15; ++k) bl += wk.w[k] * win[k];
            float c = x2[(ly0 + j + 7) * X2P + tx + 8];
            float v = s * bl + (1.0f - s) * c;
            int gy = y0 + ly0 + j;
            float gyf = -1.0f + 2.0f * (float)gy * (1.0f / (float)(HH - 1));
            float mask = __fdividef(1.0f, 1.0f + __expf(hard * (base + gyf * sth)));
            v = v * (1.0f - inten * mask);
            v = fminf(fmaxf(v, 0.0f), 1.0f);
            dstP[(size_t)gy * WW + gx] = v;
#pragma unroll
            for (int k = 0; k < 14; ++k) win[k] = win[k + 1];
        }
    }
}

extern "C" void kernel_launch(void* const* d_in, const int* in_sizes, int n_in,
                              void* d_out, int out_size, void* d_ws, size_t ws_size,
                              hipStream_t stream)
{
    const float* x       = (const float*)d_in[0];
    const float* gains   = (const float*)d_in[1];
    const float* p_gamma = (const float*)d_in[2];
    const float* p_sb    = (const float*)d_in[3];
    const float* p_hr    = (const float*)d_in[4];
    const float* p_br    = (const float*)d_in[5];
    const float* p_ct    = (const float*)d_in[6];
    const float* p_enh   = (const float*)d_in[7];
    const float* p_soft  = (const float*)d_in[8];
    const float* p_int   = (const float*)d_in[9];
    const float* p_rot   = (const float*)d_in[10];
    const float* p_hard  = (const float*)d_in[11];

    W15 wk;
    {
        double g[15], sum = 0.0;
        for (int i = 0; i < 15; ++i) { double d = (double)(i - 7); g[i] = exp(-d * d / 18.0); sum += g[i]; }
        for (int i = 0; i < 15; ++i) wk.w[i] = (float)(g[i] / sum);
    }

    dim3 grid(WW / TW, HH / TH, NPLANES);   // 16 x 32 x 12 = 6144 blocks
    k_mega<<<grid, dim3(256), 0, stream>>>(
        x, (float*)d_out, gains, p_gamma, p_sb, p_hr, p_br, p_ct,
        p_enh, p_soft, p_int, p_rot, p_hard, wk);
}

// Round 6
// 219.574 us; speedup vs baseline: 1.1880x; 1.1880x over previous
//
#include <hip/hip_runtime.h>
#include <math.h>

#define HH 1024
#define WW 1024
#define NPLANES 12              // B*C = 4*3
#define PLANE (HH * WW)

#define TW 64                   // output tile width
#define TH 64                   // output tile height
#define HR 78                   // h-blurred rows needed = TH + 14
#define PITCH 68                // LDS row pitch (floats) — proven 0-conflict (R3)

struct W15 { float w[15]; };

// zero-padded aligned float4 row load (x must be multiple of 4)
__device__ inline float4 ld4z(const float* __restrict__ row, int x) {
    if (x >= 0 && x + 3 < WW) return *(const float4*)(row + x);
    float4 r; float* p = (float*)&r;
#pragma unroll
    for (int j = 0; j < 4; ++j) { int xx = x + j; p[j] = (xx >= 0 && xx < WW) ? row[xx] : 0.0f; }
    return r;
}

__device__ inline float chain1(float t, float gain, float gamma, float sb,
                               float hr, float br, float ct) {
    t = t * gain;
    t = __builtin_amdgcn_exp2f(gamma * __log2f(t));          // pow(t,gamma), t>=0
    float hi = __fdividef(1.0f, 1.0f + __expf((0.5f - t) * 10.0f));
    t = t + sb * (1.0f - hi) - hr * hi;
    t = fminf(fmaxf(t, 0.0f), 1.0f);
    t = ct * (t - 0.5f) + 0.5f + br;
    return fminf(fmaxf(t, 0.0f), 1.0f);
}

__device__ inline float4 hdot4(const float f[20], const W15& wk) {
    float4 o; float* po = (float*)&o;
#pragma unroll
    for (int j = 0; j < 4; ++j) {
        float acc = 0.0f;
#pragma unroll
        for (int k = 0; k < 15; ++k) acc += wk.w[k] * f[j + 1 + k];
        po[j] = acc;
    }
    return o;
}

// ========== K2: in-register chain + h-blur -> LDS; v-blur + LCE -> x2 =========
// x2 = (1+e)*t0 - e*blur15(t0),  t0 = chain(x) computed in registers.
__global__ __launch_bounds__(256) void k_chain_lce(
    const float* __restrict__ x, float* __restrict__ x2o,
    const float* __restrict__ gains,
    const float* __restrict__ pg, const float* __restrict__ psb,
    const float* __restrict__ phr, const float* __restrict__ pbr,
    const float* __restrict__ pct, const float* __restrict__ penh, W15 wk)
{
    __shared__ float hbl[HR * PITCH];    // 21.2 KB, h-blurred t0
    __shared__ float t0s[TH * PITCH];    // 17.4 KB, chained centers
    const int p   = blockIdx.z;
    const int x0  = blockIdx.x * TW;
    const int y0  = blockIdx.y * TH;
    const int tid = threadIdx.x;
    const float* plane = x + (size_t)p * PLANE;

    const float gain  = gains[p % 3];
    const float gamma = *pg, sb = *psb, hr = *phr, br = *pbr, ct = *pct;
    const float e     = *penh;

    const bool edge = (blockIdx.x == 0) || (blockIdx.x == WW / TW - 1) ||
                      (blockIdx.y == 0) || (blockIdx.y == HH / TH - 1);
    const int cx = (tid & 15) * 4;       // 0..60
    const int r0 = tid >> 4;             // 0..15

    if (!edge) {
        // ---- fast path: unconditional loads, no masks ----
#pragma unroll
        for (int it = 0; it < 5; ++it) {
            int r = r0 + 16 * it;
            if (r < HR) {
                const float* rp = plane + (size_t)(y0 - 7 + r) * WW + (x0 + cx - 8);
                float f[20];
                *(float4*)&f[0]  = *(const float4*)(rp);
                *(float4*)&f[4]  = *(const float4*)(rp + 4);
                *(float4*)&f[8]  = *(const float4*)(rp + 8);
                *(float4*)&f[12] = *(const float4*)(rp + 12);
                *(float4*)&f[16] = *(const float4*)(rp + 16);
#pragma unroll
                for (int m = 0; m < 20; ++m) f[m] = chain1(f[m], gain, gamma, sb, hr, br, ct);
                if (r >= 7 && r < 7 + TH) *(float4*)&t0s[(r - 7) * PITCH + cx] = *(float4*)&f[8];
                *(float4*)&hbl[r * PITCH + cx] = hdot4(f, wk);
            }
        }
    } else {
        // ---- edge path: guarded loads + post-chain zero masking ----
        for (int it = 0; it < 5; ++it) {
            int r = r0 + 16 * it;
            if (r < HR) {
                int gy = y0 - 7 + r;
                float4 o;
                if (gy >= 0 && gy < HH) {
                    const float* row = plane + (size_t)gy * WW;
                    int xb = x0 + cx - 8;
                    float f[20];
                    *(float4*)&f[0]  = ld4z(row, xb);
                    *(float4*)&f[4]  = ld4z(row, xb + 4);
                    *(float4*)&f[8]  = ld4z(row, xb + 8);
                    *(float4*)&f[12] = ld4z(row, xb + 12);
                    *(float4*)&f[16] = ld4z(row, xb + 16);
#pragma unroll
                    for (int m = 0; m < 20; ++m) {
                        float cv = chain1(f[m], gain, gamma, sb, hr, br, ct);
                        int xx = xb + m;
                        f[m] = (xx >= 0 && xx < WW) ? cv : 0.0f;   // conv zero-pad
                    }
                    if (r >= 7 && r < 7 + TH) *(float4*)&t0s[(r - 7) * PITCH + cx] = *(float4*)&f[8];
                    o = hdot4(f, wk);
                } else {
                    o = make_float4(0.0f, 0.0f, 0.0f, 0.0f);       // pad rows
                }
                *(float4*)&hbl[r * PITCH + cx] = o;
            }
        }
    }
    __syncthreads();

    // ---- phase 2: vertical 15-tap + LCE, centers from t0s LDS ---------------
    const int tx  = tid & 63;
    const int ty  = tid >> 6;
    const int ly0 = ty * 16;

    float win[15];
#pragma unroll
    for (int k = 0; k < 15; ++k) win[k] = hbl[(ly0 + k) * PITCH + tx];

    float* dstP = x2o + (size_t)p * PLANE;
#pragma unroll
    for (int j = 0; j < 16; ++j) {
        int y = y0 + ly0 + j;
        float lm = 0.0f;
#pragma unroll
        for (int k = 0; k < 15; ++k) lm += wk.w[k] * win[k];
        float c = t0s[(ly0 + j) * PITCH + tx];
        dstP[(size_t)y * WW + x0 + tx] = (1.0f + e) * c - e * lm;
#pragma unroll
        for (int k = 0; k < 14; ++k) win[k] = win[k + 1];
        win[14] = hbl[(ly0 + j + 15) * PITCH + tx];
    }
}

// ========== K3: separable blur + softness + gradient mask + clip -> out =======
__global__ __launch_bounds__(256) void k_blur_final(
    const float* __restrict__ src, float* __restrict__ dst,
    const float* __restrict__ psoft, const float* __restrict__ pint,
    const float* __restrict__ prot, const float* __restrict__ phard, W15 wk)
{
    __shared__ float hbl[HR * PITCH];
    const int p   = blockIdx.z;
    const int x0  = blockIdx.x * TW;
    const int y0  = blockIdx.y * TH;
    const int tid = threadIdx.x;
    const float* plane = src + (size_t)p * PLANE;

    const bool edge = (blockIdx.x == 0) || (blockIdx.x == WW / TW - 1) ||
                      (blockIdx.y == 0) || (blockIdx.y == HH / TH - 1);
    const int cx = (tid & 15) * 4;
    const int r0 = tid >> 4;

    if (!edge) {
#pragma unroll
        for (int it = 0; it < 5; ++it) {
            int r = r0 + 16 * it;
            if (r < HR) {
                const float* rp = plane + (size_t)(y0 - 7 + r) * WW + (x0 + cx - 8);
                float f[20];
                *(float4*)&f[0]  = *(const float4*)(rp);
                *(float4*)&f[4]  = *(const float4*)(rp + 4);
                *(float4*)&f[8]  = *(const float4*)(rp + 8);
                *(float4*)&f[12] = *(const float4*)(rp + 12);
                *(float4*)&f[16] = *(const float4*)(rp + 16);
                *(float4*)&hbl[r * PITCH + cx] = hdot4(f, wk);
            }
        }
    } else {
        for (int it = 0; it < 5; ++it) {
            int r = r0 + 16 * it;
            if (r < HR) {
                int gy = y0 - 7 + r;
                float4 o;
                if (gy >= 0 && gy < HH) {
                    const float* row = plane + (size_t)gy * WW;
                    int xb = x0 + cx - 8;
                    float f[20];
                    *(float4*)&f[0]  = ld4z(row, xb);
                    *(float4*)&f[4]  = ld4z(row, xb + 4);
                    *(float4*)&f[8]  = ld4z(row, xb + 8);
                    *(float4*)&f[12] = ld4z(row, xb + 12);
                    *(float4*)&f[16] = ld4z(row, xb + 16);
                    o = hdot4(f, wk);
                } else {
                    o = make_float4(0.0f, 0.0f, 0.0f, 0.0f);
                }
                *(float4*)&hbl[r * PITCH + cx] = o;
            }
        }
    }
    __syncthreads();

    const int tx  = tid & 63;
    const int ty  = tid >> 6;
    const int ly0 = ty * 16;
    const int gx  = x0 + tx;

    const float s     = *psoft;
    const float inten = *pint;
    const float hard  = *phard;
    const float theta = (*prot) * 0.017453292519943295f;
    const float cth = __cosf(theta), sth = __sinf(theta);
    const float base = (-1.0f + 2.0f * (float)gx * (1.0f / (float)(WW - 1))) * cth;

    float win[15];
#pragma unroll
    for (int k = 0; k < 15; ++k) win[k] = hbl[(ly0 + k) * PITCH + tx];

    float* dstP = dst + (size_t)p * PLANE;
#pragma unroll
    for (int j = 0; j < 16; ++j) {
        int y = y0 + ly0 + j;
        float bl = 0.0f;
#pragma unroll
        for (int k = 0; k < 15; ++k) bl += wk.w[k] * win[k];
        float c = plane[(size_t)y * WW + gx];              // x2 center (L2-hot)
        float v = s * bl + (1.0f - s) * c;
        float gyf = -1.0f + 2.0f * (float)y * (1.0f / (float)(HH - 1));
        float mask = __fdividef(1.0f, 1.0f + __expf(hard * (base + gyf * sth)));
        v = v * (1.0f - inten * mask);
        v = fminf(fmaxf(v, 0.0f), 1.0f);
        dstP[(size_t)y * WW + gx] = v;
#pragma unroll
        for (int k = 0; k < 14; ++k) win[k] = win[k + 1];
        win[14] = hbl[(ly0 + j + 15) * PITCH + tx];
    }
}

extern "C" void kernel_launch(void* const* d_in, const int* in_sizes, int n_in,
                              void* d_out, int out_size, void* d_ws, size_t ws_size,
                              hipStream_t stream)
{
    const float* x       = (const float*)d_in[0];
    const float* gains   = (const float*)d_in[1];
    const float* p_gamma = (const float*)d_in[2];
    const float* p_sb    = (const float*)d_in[3];
    const float* p_hr    = (const float*)d_in[4];
    const float* p_br    = (const float*)d_in[5];
    const float* p_ct    = (const float*)d_in[6];
    const float* p_enh   = (const float*)d_in[7];
    const float* p_soft  = (const float*)d_in[8];
    const float* p_int   = (const float*)d_in[9];
    const float* p_rot   = (const float*)d_in[10];
    const float* p_hard  = (const float*)d_in[11];

    float* X2  = (float*)d_ws;    // x2 intermediate (50.3 MB)
    float* OUT = (float*)d_out;

    W15 wk;
    {
        double g[15], sum = 0.0;
        for (int i = 0; i < 15; ++i) { double d = (double)(i - 7); g[i] = exp(-d * d / 18.0); sum += g[i]; }
        for (int i = 0; i < 15; ++i) wk.w[i] = (float)(g[i] / sum);
    }

    dim3 grid(WW / TW, HH / TH, NPLANES);   // 16 x 16 x 12
    // K2: x -> X2  (chain in registers + blur + local contrast)
    k_chain_lce<<<grid, dim3(256), 0, stream>>>(
        x, X2, gains, p_gamma, p_sb, p_hr, p_br, p_ct, p_enh, wk);
    // K3: X2 -> OUT (blur + softness + gradient + clip)
    k_blur_final<<<grid, dim3(256), 0, stream>>>(
        X2, OUT, p_soft, p_int, p_rot, p_hard, wk);
}